// Round 12
// baseline (155.567 us; speedup 1.0000x reference)
//
#include <hip/hip_runtime.h>

// Problem constants: B=1, N=16, T=2048, E=64, H=4, D=16
#define N_ 16
#define T_ 2048
#define E_ 64
#define H_ 4
#define D_ 16
#define NH_ 64            // N_*H_
#define SEXP_ 0.18033688f // 0.125 * log2(e):  exp(s/8) == exp2(s*SEXP_)

typedef __attribute__((ext_vector_type(4))) _Float16 h4;
typedef __attribute__((ext_vector_type(8))) _Float16 h8;
typedef __attribute__((ext_vector_type(2))) __fp16 g2;
typedef __attribute__((ext_vector_type(4))) float f4;
typedef __attribute__((ext_vector_type(2))) float f2;

#if __has_builtin(__builtin_amdgcn_exp2f)
__device__ inline float fast_exp2(float x) { return __builtin_amdgcn_exp2f(x); }
#else
__device__ inline float fast_exp2(float x) {
    float r; asm("v_exp_f32 %0, %1" : "=v"(r) : "v"(x)); return r;
}
#endif

#if __has_builtin(__builtin_amdgcn_rcpf)
__device__ inline float fast_rcp(float x) { return __builtin_amdgcn_rcpf(x); }
#else
__device__ inline float fast_rcp(float x) {
    float r; asm("v_rcp_f32 %0, %1" : "=v"(r) : "v"(x)); return r;
}
#endif

__device__ inline h4 pack4_f16(float a, float b, float c, float d) {
    union { g2 g[2]; h4 h; } u;
    u.g[0] = __builtin_amdgcn_cvt_pkrtz(a, b);
    u.g[1] = __builtin_amdgcn_cvt_pkrtz(c, d);
    return u.h;
}

// ---------------------------------------------------------------------------
// K1: fused projections (y=0 Q pre-scaled, y=1 K, y=2 V-transposed, y=3 Wfc^T)
// ---------------------------------------------------------------------------
__global__ __launch_bounds__(256) void proj_kernel(
    const float* __restrict__ xq, const float* __restrict__ Wq, const float* __restrict__ bq,
    const float* __restrict__ xk, const float* __restrict__ Wk, const float* __restrict__ bk,
    const float* __restrict__ xv, const float* __restrict__ Wv, const float* __restrict__ bv,
    const float* __restrict__ Wfc,
    _Float16* __restrict__ Qh, _Float16* __restrict__ Kh, _Float16* __restrict__ Vt,
    _Float16* __restrict__ Wt)
{
    int tid = threadIdx.x;
    int y = blockIdx.y;
    if (y == 3) {
        if (blockIdx.x < 16) {
            int k = blockIdx.x * 4 + (tid >> 6);
            int e = tid & 63;
            Wt[e * 64 + k] = (_Float16)Wfc[k * 64 + e];
        }
        return;
    }
    const float* x = (y == 0) ? xq : (y == 1) ? xk : xv;
    const float* W = (y == 0) ? Wq : (y == 1) ? Wk : Wv;
    const float* b = (y == 0) ? bq : (y == 1) ? bk : bv;
    const float sc = (y == 0) ? SEXP_ : 1.0f;

    __shared__ float Wl[D_ * D_];
    __shared__ float bl[D_];
    Wl[tid] = W[tid];
    if (tid < D_) bl[tid] = b[tid];
    __syncthreads();

    int r = blockIdx.x * 256 + tid;
    int h, t, n;
    if (y == 2) {          // t fastest: coalesced transposed stores
        t = r & (T_ - 1);
        h = (r >> 11) & (H_ - 1);
        n = r >> 13;
    } else {               // h fastest: coalesced reads
        h = r & (H_ - 1);
        t = (r >> 2) & (T_ - 1);
        n = r >> 13;
    }

    const float4* xp4 = reinterpret_cast<const float4*>(
        x + ((size_t)(n * T_ + t) * E_ + h * D_));
    float xv_[D_];
#pragma unroll
    for (int i = 0; i < 4; i++) {
        float4 v = xp4[i];
        xv_[4*i] = v.x; xv_[4*i+1] = v.y; xv_[4*i+2] = v.z; xv_[4*i+3] = v.w;
    }
    float acc[D_];
#pragma unroll
    for (int i = 0; i < D_; i++) acc[i] = bl[i];
#pragma unroll
    for (int j = 0; j < D_; j++) {
        float xj = xv_[j];
#pragma unroll
        for (int i = 0; i < D_; i++) acc[i] = fmaf(xj, Wl[j * D_ + i], acc[i]);
    }
    if (y == 2) {
        _Float16* vb = Vt + (size_t)(n * H_ + h) * D_ * T_ + t;
#pragma unroll
        for (int d = 0; d < D_; d++) vb[(size_t)d * T_] = (_Float16)acc[d];
    } else {
        _Float16 ob[16];
#pragma unroll
        for (int i = 0; i < D_; i++) ob[i] = (_Float16)(acc[i] * sc);
        _Float16* o = (y == 0) ? Qh : Kh;
        uint4* dst = reinterpret_cast<uint4*>(o + (size_t)((n * H_ + h) * T_ + t) * D_);
        dst[0] = reinterpret_cast<uint4*>(ob)[0];
        dst[1] = reinterpret_cast<uint4*>(ob)[1];
    }
}

// ---------------------------------------------------------------------------
// K2: single-pass fused stats+attn, v9 = R10/R11 (verified 62.9-63.7us, DPP
//   reduce + setprio, PO f16, 64 VGPR no-spill) + two tail micro-cuts:
//   (1) lp accumulation via float2 -> v_pk_add_f32 (32 adds -> 16 pk-adds
//       per chunk on the full-rate packed-f32 pipe).
//   (2) l[bp1] zero hoisted to iteration TOP: ordering only needs iter c-1's
//       barrier (bp1(c)=bm1(c-1), last read before that barrier; next writers
//       beyond iter c's barrier) — removes it from the pre-barrier tail that
//       the last wave gates.
//   Roofline note: 268M exp2 / 1024 SIMDs at ~32cyc/wave64 = ~55us chip-wide
//   trans floor; attn is ~86% there.  The compressible remainder is this
//   VALU/reduce tail (R10's DPP cut: -7us).
//   REGISTER BUDGET: 64 arch VGPR at waves_per_eu(4,4) (R4-R11 evidence).
//   Spill tell: WRITE_SIZE >> 19 MB.
// ---------------------------------------------------------------------------
#define S_PHASE(PD) do {                                                      \
    lp01 = (f2){0.f, 0.f}; lp23 = (f2){0.f, 0.f};                             \
    _Pragma("unroll")                                                         \
    for (int j = 0; j < 8; j++) {                                             \
        h4 bj = *reinterpret_cast<const h4*>(QsW + (j * 16 + row) * 20 + quad * 4); \
        f4 s = __builtin_amdgcn_mfma_f32_16x16x16f16(a, bj, z4, 0, 0, 0);     \
        float e0 = fast_exp2(s[0]), e1 = fast_exp2(s[1]);                     \
        float e2 = fast_exp2(s[2]), e3 = fast_exp2(s[3]);                     \
        lp01 += (f2){e0, e1}; lp23 += (f2){e2, e3};                           \
        PD[j] = pack4_f16(e0, e1, e2, e3);                                    \
    }                                                                         \
} while (0)

// DPP row_shr:N accumulate (old=0, bound_ctrl=true -> OOB lanes add 0).
#define DPP_ADD(X, CTRL) do {                                                 \
    int t_ = __builtin_amdgcn_update_dpp(0, __float_as_int(X), CTRL, 0xF, 0xF, true); \
    X += __int_as_float(t_);                                                  \
} while (0)

// After shr 1,2,4,8: lane i = sum(orig[i-15..i]) within its 16-lane DPP row
// (= quad group, rows 0..15) -> ROW 15 holds the full row sum.
#define DPP_TREE(X)                                                           \
    DPP_ADD(X, 0x111); DPP_ADD(X, 0x112); DPP_ADD(X, 0x114); DPP_ADD(X, 0x118);

#define REDUCE(BDST) do {                                                     \
    float r0_ = lp01[0], r1_ = lp01[1], r2_ = lp23[0], r3_ = lp23[1];         \
    DPP_TREE(r0_) DPP_TREE(r1_) DPP_TREE(r2_) DPP_TREE(r3_)                   \
    if (row == 15) {                                                          \
        atomicAdd(&l[BDST][quad * 4 + 0], r0_);                               \
        atomicAdd(&l[BDST][quad * 4 + 1], r1_);                               \
        atomicAdd(&l[BDST][quad * 4 + 2], r2_);                               \
        atomicAdd(&l[BDST][quad * 4 + 3], r3_);                               \
    }                                                                         \
} while (0)

// iter C: zero l[bp1] (top — see header), S(C)->PS, reduce(C)->l[b0],
// rcp+scale, PV(C-1) from PPV (setprio-wrapped), barrier.
#define ITER(C, PS, PPV, KN) do {                                             \
    int k0 = k_lo + (C) * 16;                                                 \
    if (wave == 0 && lane < 16) l[bp1][lane] = 0.f;                           \
    h4 v = *reinterpret_cast<const h4*>(Vb + (k0 - 16) + quad * 4);           \
    f4 la = *reinterpret_cast<f4*>(&l[bm1][quad * 4]);                        \
    S_PHASE(PS);                                                              \
    h4 na = *reinterpret_cast<const h4*>(Kb + ((KN) + row) * D_ + quad * 4);  \
    REDUCE(b0);                                                               \
    {                                                                         \
        union { g2 g[2]; h4 h; } u_;                                          \
        u_.g[0] = __builtin_amdgcn_cvt_pkrtz(fast_rcp(la[0]), fast_rcp(la[1])); \
        u_.g[1] = __builtin_amdgcn_cvt_pkrtz(fast_rcp(la[2]), fast_rcp(la[3])); \
        v = v * u_.h;                                                         \
    }                                                                         \
    __builtin_amdgcn_s_setprio(1);                                            \
    _Pragma("unroll")                                                         \
    for (int j = 0; j < 8; j++)                                               \
        o[j] = __builtin_amdgcn_mfma_f32_16x16x16f16(PPV[j], v, o[j], 0, 0, 0); \
    __builtin_amdgcn_s_setprio(0);                                            \
    __syncthreads();                                                          \
    a = na;                                                                   \
} while (0)

#define ROT() do { int t_ = bm1; bm1 = b0; b0 = bp1; bp1 = t_; } while (0)

__global__ __attribute__((amdgpu_flat_work_group_size(1024, 1024)))
           __attribute__((amdgpu_waves_per_eu(4, 4)))
void fused_attn_kernel(
    const _Float16* __restrict__ Qh, const _Float16* __restrict__ Kh,
    const _Float16* __restrict__ Vt, _Float16* __restrict__ PO)
{
    __shared__ __align__(16) _Float16 Qs[16 * 128 * 20];   // 80 KB, stride 20
    __shared__ __align__(16) float l[3][16];
    int tid = threadIdx.x;
    int lane = tid & 63, wave = tid >> 6;          // wave 0..15
    int row = lane & 15, quad = lane >> 4;
    int nh = blockIdx.x;
    int z = blockIdx.y;
    int k_lo = z * (T_ / 4);

    const _Float16* Kb = Kh + (size_t)nh * T_ * D_;
    const _Float16* Qb = Qh + (size_t)nh * T_ * D_;
    const _Float16* Vb = Vt + (size_t)nh * D_ * T_ + (size_t)row * T_;

    if (tid < 48) ((float*)l)[tid] = 0.f;

    // stage ALL Q rows for this block (16 waves x 128 rows x 16 halfs) into
    // padded LDS.  Global source is exactly linear in u; LDS dst uint2 index
    // = rr*5 + slot  (20-half row stride).
    {
        const uint2* src = reinterpret_cast<const uint2*>(Qb);
        uint2* dq = reinterpret_cast<uint2*>(Qs);
#pragma unroll
        for (int s = 0; s < 8; s++) {
            int u = s * 1024 + tid;
            dq[(u >> 2) * 5 + (u & 3)] = src[u];
        }
    }
    const _Float16* QsW = Qs + wave * (128 * 20);

    f4 o[8];
#pragma unroll
    for (int j = 0; j < 8; j++) o[j] = (f4){0.f, 0.f, 0.f, 0.f};
    f4 z4 = {0.f, 0.f, 0.f, 0.f};

    h4 a = *reinterpret_cast<const h4*>(Kb + (k_lo + row) * D_ + quad * 4);
    h4 pA[8], pB[8];
    f2 lp01, lp23;

    __syncthreads();   // l zero-init + Qs staging visible

    // ---- chunk 0 prologue: S -> pA, reduce -> buf 0 (no PV yet)
    S_PHASE(pA);
    {
        h4 na = *reinterpret_cast<const h4*>(Kb + (k_lo + 16 + row) * D_ + quad * 4);
        REDUCE(0);
        __syncthreads();
        a = na;
    }

    int bm1 = 0, b0 = 1, bp1 = 2;
#pragma unroll 1
    for (int c = 1; c < 31; c += 2) {
        ITER(c,     pB, pA, k_lo + c * 16 + 16);
        ROT();
        ITER(c + 1, pA, pB, k_lo + c * 16 + 32);
        ROT();
    }
    ITER(31, pB, pA, k_lo);   // K prefetch wraps (harmless)
    ROT();

    // ---- final PV(31) from pB
    {
        h4 v = *reinterpret_cast<const h4*>(Vb + (k_lo + 31 * 16) + quad * 4);
        f4 la = *reinterpret_cast<f4*>(&l[bm1][quad * 4]);
        union { g2 g[2]; h4 h; } u_;
        u_.g[0] = __builtin_amdgcn_cvt_pkrtz(fast_rcp(la[0]), fast_rcp(la[1]));
        u_.g[1] = __builtin_amdgcn_cvt_pkrtz(fast_rcp(la[2]), fast_rcp(la[3]));
        v = v * u_.h;
#pragma unroll
        for (int j = 0; j < 8; j++)
            o[j] = __builtin_amdgcn_mfma_f32_16x16x16f16(pB[j], v, o[j], 0, 0, 0);
    }

    int n = nh >> 2, h = nh & 3;
    _Float16* po = PO + (size_t)z * N_ * T_ * E_ + (size_t)n * T_ * E_ + h * D_ + row;
#pragma unroll
    for (int j = 0; j < 8; j++)
#pragma unroll
        for (int i = 0; i < 4; i++) {
            int q0 = (wave * 8 + j) * 16 + quad * 4 + i;
            po[(size_t)q0 * E_] = (_Float16)o[j][i];
        }
}

// ---------------------------------------------------------------------------
// K4: fc — out = (sum_z PO[z]) @ Wfc + bfc via 16x16x32 MFMA on Wt.
//     PO f16: one h8 (16B) load per (z, half); z-sum in f32 after convert.
//     wave: one 16-row M-tile; 2048 tiles -> 512 blocks.
// ---------------------------------------------------------------------------
__global__ __launch_bounds__(256) void fc_kernel(
    const _Float16* __restrict__ PO, const _Float16* __restrict__ Wt,
    const float* __restrict__ bfc, float* __restrict__ out)
{
    int tid = threadIdx.x;
    int lane = tid & 63, wave = tid >> 6;
    int row = lane & 15, quad = lane >> 4;
    int g = blockIdx.x * 4 + wave;             // M-tile id, 2048 total
    int r0 = g * 16;
    size_t base = (size_t)(r0 + row) * E_;             // halfs
    const size_t zstrideh = (size_t)N_ * T_ * E_;      // halfs per z-slice

    h8 a[2];
#pragma unroll
    for (int half = 0; half < 2; half++) {
        f4 u0 = {0.f,0.f,0.f,0.f}, u1 = {0.f,0.f,0.f,0.f};
#pragma unroll
        for (int zz = 0; zz < 4; zz++) {
            h8 w = *reinterpret_cast<const h8*>(
                PO + zz * zstrideh + base + half * 32 + quad * 8);
#pragma unroll
            for (int i = 0; i < 4; i++) {
                u0[i] += (float)w[i];
                u1[i] += (float)w[i + 4];
            }
        }
        union { h4 h[2]; h8 v; } pk;
        pk.h[0] = pack4_f16(u0[0], u0[1], u0[2], u0[3]);
        pk.h[1] = pack4_f16(u1[0], u1[1], u1[2], u1[3]);
        a[half] = pk.v;
    }
    f4 acc[4];
#pragma unroll
    for (int ne = 0; ne < 4; ne++) {
        const _Float16* wtb = Wt + (size_t)(ne * 16 + row) * 64;
        h8 b0 = *reinterpret_cast<const h8*>(wtb + quad * 8);
        h8 b1 = *reinterpret_cast<const h8*>(wtb + 32 + quad * 8);
        acc[ne] = __builtin_amdgcn_mfma_f32_16x16x32_f16(a[0], b0, (f4){0.f,0.f,0.f,0.f}, 0, 0, 0);
        acc[ne] = __builtin_amdgcn_mfma_f32_16x16x32_f16(a[1], b1, acc[ne], 0, 0, 0);
    }
#pragma unroll
    for (int ne = 0; ne < 4; ne++) {
        float bias = bfc[ne * 16 + row];
#pragma unroll
        for (int i = 0; i < 4; i++)
            out[(size_t)(r0 + quad * 4 + i) * E_ + ne * 16 + row] = acc[ne][i] + bias;
    }
}

extern "C" void kernel_launch(void* const* d_in, const int* in_sizes, int n_in,
                              void* d_out, int out_size, void* d_ws, size_t ws_size,
                              hipStream_t stream) {
    (void)in_sizes; (void)n_in; (void)out_size; (void)ws_size;
    const float* value = (const float*)d_in[0];
    const float* key   = (const float*)d_in[1];
    const float* query = (const float*)d_in[2];
    const float* Wq    = (const float*)d_in[3];
    const float* bq    = (const float*)d_in[4];
    const float* Wk    = (const float*)d_in[5];
    const float* bk    = (const float*)d_in[6];
    const float* Wv    = (const float*)d_in[7];
    const float* bv    = (const float*)d_in[8];
    const float* Wfc   = (const float*)d_in[9];
    const float* bfc   = (const float*)d_in[10];
    float* out = (float*)d_out;

    // ws bytes: Qh 0-4M | Kh 4-8M | Vt 8-12M | Wt 12M | PO 15-32M (f16)
    char* ws = (char*)d_ws;
    _Float16* Qh  = (_Float16*)(ws);
    _Float16* Kh  = (_Float16*)(ws + (4u << 20));
    _Float16* Vt  = (_Float16*)(ws + (8u << 20));
    _Float16* Wt  = (_Float16*)(ws + (12u << 20));
    _Float16* PO  = (_Float16*)(ws + (15u << 20));

    proj_kernel<<<dim3(512, 4), 256, 0, stream>>>(
        query, Wq, bq, key, Wk, bk, value, Wv, bv, Wfc, Qh, Kh, Vt, Wt);
    fused_attn_kernel<<<dim3(NH_, 4), 1024, 0, stream>>>(Qh, Kh, Vt, PO);
    fc_kernel<<<512, 256, 0, stream>>>(PO, Wt, bfc, out);
}